// Round 3
// baseline (2742.975 us; speedup 1.0000x reference)
//
#include <hip/hip_runtime.h>
#include <hip/hip_bf16.h>

#define NN 100000
#define NE 1600000
#define DIM 128
#define BM 64

typedef __attribute__((ext_vector_type(8))) short short8;
typedef __attribute__((ext_vector_type(4))) float f32x4;

__device__ __forceinline__ unsigned short f2bf(float f) {
  union { float f; unsigned u; } v; v.f = f;
  unsigned r = v.u + 0x7fffu + ((v.u >> 16) & 1u);
  return (unsigned short)(r >> 16);
}

// --- prep: W fp32 -> bf16, bias sum ---------------------------------------
__global__ void prep_kernel(const float* __restrict__ Wn, const float* __restrict__ bn,
                            const float* __restrict__ Ws, const float* __restrict__ bs,
                            unsigned short* __restrict__ wnb, unsigned short* __restrict__ wsb,
                            float* __restrict__ bsum) {
  int tid = blockIdx.x * blockDim.x + threadIdx.x;
  int stride = gridDim.x * blockDim.x;
  for (int i = tid; i < DIM * DIM; i += stride) {
    wnb[i] = f2bf(Wn[i]);
    wsb[i] = f2bf(Ws[i]);
  }
  if (tid < DIM) bsum[tid] = bn[tid] + bs[tid];
}

// --- scatter: acc[dst] += x[src], 32 lanes per edge, float4 per lane -------
__global__ __launch_bounds__(256) void scatter_kernel(const float* __restrict__ x,
                                                      const int* __restrict__ ei,
                                                      float* __restrict__ acc) {
  int e = blockIdx.x * 8 + (threadIdx.x >> 5);
  if (e >= NE) return;
  int lane = threadIdx.x & 31;
  int src = ei[e];
  int dst = ei[NE + e];
  // defensive: any index-dtype surprise degrades to wrong-answer, not fault
  if ((unsigned)src >= NN || (unsigned)dst >= NN) return;
  f32x4 v = *reinterpret_cast<const f32x4*>(x + (size_t)src * DIM + lane * 4);
  float* d = acc + (size_t)dst * DIM + lane * 4;
  atomicAdd(d + 0, v[0]);
  atomicAdd(d + 1, v[1]);
  atomicAdd(d + 2, v[2]);
  atomicAdd(d + 3, v[3]);
}

// --- fused GEMM: out = neigh@Wn^T + x@Ws^T + (bn+bs), in-place on out -----
// LDS: sW 32KB + sA 16KB + sX 16KB = 64KB. XOR swizzle (row&7)<<4 on byte
// offsets kills the stride-256B 16-way bank conflict on ds_read_b128.
__global__ __launch_bounds__(256) void gemm_kernel(const float* __restrict__ x,
    float* __restrict__ out,
    const unsigned short* __restrict__ wnb, const unsigned short* __restrict__ wsb,
    const float* __restrict__ bsum) {
  __shared__ unsigned short sW[DIM * DIM];  // 32KB
  __shared__ unsigned short sA[BM * DIM];   // 16KB neigh tile (bf16)
  __shared__ unsigned short sX[BM * DIM];   // 16KB x tile (bf16)
  const int tid = threadIdx.x;
  const int row0 = blockIdx.x * BM;

  // stage neigh (from out, in-place) + x tiles, fp32 -> bf16, swizzled
  #pragma unroll
  for (int it = 0; it < 4; ++it) {
    int id = it * 256 + tid;
    int r = id >> 4;              // 16 chunks of 8 elems per 128-wide row
    int k0 = (id & 15) << 3;
    int gr = row0 + r;
    short8 an = (short8)0, ax = (short8)0;
    if (gr < NN) {
      const f32x4* pn = reinterpret_cast<const f32x4*>(out + (size_t)gr * DIM + k0);
      f32x4 n0 = pn[0], n1 = pn[1];
      const f32x4* px = reinterpret_cast<const f32x4*>(x + (size_t)gr * DIM + k0);
      f32x4 x0 = px[0], x1 = px[1];
      #pragma unroll
      for (int j = 0; j < 4; ++j) {
        an[j]     = (short)f2bf(n0[j]);
        an[4 + j] = (short)f2bf(n1[j]);
        ax[j]     = (short)f2bf(x0[j]);
        ax[4 + j] = (short)f2bf(x1[j]);
      }
    }
    int off = (r * 256 + k0 * 2) ^ ((r & 7) << 4);
    *reinterpret_cast<short8*>(reinterpret_cast<char*>(sA) + off) = an;
    *reinterpret_cast<short8*>(reinterpret_cast<char*>(sX) + off) = ax;
  }
  // stage Wn (already bf16 in ws)
  #pragma unroll
  for (int it = 0; it < 8; ++it) {
    int id = it * 256 + tid;
    int r = id >> 4;
    int k0 = (id & 15) << 3;
    short8 w = *reinterpret_cast<const short8*>(wnb + r * DIM + k0);
    int off = (r * 256 + k0 * 2) ^ ((r & 7) << 4);
    *reinterpret_cast<short8*>(reinterpret_cast<char*>(sW) + off) = w;
  }
  __syncthreads();

  const int wave = tid >> 6;
  const int lane = tid & 63;
  const int arow = wave * 16 + (lane & 15);   // A row within tile
  const int kl = (lane >> 4) * 8;             // k sub-offset within 32
  f32x4 acc[8];
  #pragma unroll
  for (int nt = 0; nt < 8; ++nt) acc[nt] = (f32x4){0.f, 0.f, 0.f, 0.f};

  // phase 1: neigh x Wn
  #pragma unroll
  for (int ks = 0; ks < 4; ++ks) {
    int k = ks * 32 + kl;
    short8 a = *reinterpret_cast<const short8*>(
        reinterpret_cast<const char*>(sA) + ((arow * 256 + k * 2) ^ ((arow & 7) << 4)));
    #pragma unroll
    for (int nt = 0; nt < 8; ++nt) {
      int o = nt * 16 + (lane & 15);
      short8 b = *reinterpret_cast<const short8*>(
          reinterpret_cast<const char*>(sW) + ((o * 256 + k * 2) ^ ((o & 7) << 4)));
      acc[nt] = __builtin_amdgcn_mfma_f32_16x16x32_bf16(a, b, acc[nt], 0, 0, 0);
    }
  }
  __syncthreads();
  // restage Ws over sW
  #pragma unroll
  for (int it = 0; it < 8; ++it) {
    int id = it * 256 + tid;
    int r = id >> 4;
    int k0 = (id & 15) << 3;
    short8 w = *reinterpret_cast<const short8*>(wsb + r * DIM + k0);
    int off = (r * 256 + k0 * 2) ^ ((r & 7) << 4);
    *reinterpret_cast<short8*>(reinterpret_cast<char*>(sW) + off) = w;
  }
  __syncthreads();
  // phase 2: x x Ws
  #pragma unroll
  for (int ks = 0; ks < 4; ++ks) {
    int k = ks * 32 + kl;
    short8 a = *reinterpret_cast<const short8*>(
        reinterpret_cast<const char*>(sX) + ((arow * 256 + k * 2) ^ ((arow & 7) << 4)));
    #pragma unroll
    for (int nt = 0; nt < 8; ++nt) {
      int o = nt * 16 + (lane & 15);
      short8 b = *reinterpret_cast<const short8*>(
          reinterpret_cast<const char*>(sW) + ((o * 256 + k * 2) ^ ((o & 7) << 4)));
      acc[nt] = __builtin_amdgcn_mfma_f32_16x16x32_bf16(a, b, acc[nt], 0, 0, 0);
    }
  }

  // epilogue: C/D layout col=lane&15, row=(lane>>4)*4+reg  [guide m89]
  #pragma unroll
  for (int nt = 0; nt < 8; ++nt) {
    int col = nt * 16 + (lane & 15);
    float bv = bsum[col];
    #pragma unroll
    for (int reg = 0; reg < 4; ++reg) {
      int gr = row0 + wave * 16 + (lane >> 4) * 4 + reg;
      if (gr < NN) out[(size_t)gr * DIM + col] = acc[nt][reg] + bv;
    }
  }
}

extern "C" void kernel_launch(void* const* d_in, const int* in_sizes, int n_in,
                              void* d_out, int out_size, void* d_ws, size_t ws_size,
                              hipStream_t stream) {
  const float* x  = (const float*)d_in[0];
  const int*   ei = (const int*)d_in[1];
  const float* Wn = (const float*)d_in[2];
  const float* bn = (const float*)d_in[3];
  const float* Ws = (const float*)d_in[4];
  const float* bs = (const float*)d_in[5];
  float* out = (float*)d_out;

  unsigned short* wnb = (unsigned short*)d_ws;          // 32KB
  unsigned short* wsb = wnb + DIM * DIM;                // 32KB
  float* bsum = (float*)(wsb + DIM * DIM);              // 512B

  // out doubles as the neigh accumulator (zero first; harness poisons it)
  hipMemsetAsync(d_out, 0, (size_t)NN * DIM * sizeof(float), stream);
  prep_kernel<<<64, 256, 0, stream>>>(Wn, bn, Ws, bs, wnb, wsb, bsum);
  scatter_kernel<<<(NE + 7) / 8, 256, 0, stream>>>(x, ei, out);
  gemm_kernel<<<(NN + BM - 1) / BM, 256, 0, stream>>>(x, out, wnb, wsb, bsum);
}

// Round 4
// 369.078 us; speedup vs baseline: 7.4320x; 7.4320x over previous
//
#include <hip/hip_runtime.h>
#include <hip/hip_bf16.h>

#define NN 100000
#define NE 1600000
#define DIM 128
#define BM 64
#define NB 391   // ceil(NN/256)

typedef __attribute__((ext_vector_type(8))) short short8;
typedef __attribute__((ext_vector_type(4))) float f32x4;

__device__ __forceinline__ unsigned short f2bf(float f) {
  union { float f; unsigned u; } v; v.f = f;
  unsigned r = v.u + 0x7fffu + ((v.u >> 16) & 1u);
  return (unsigned short)(r >> 16);
}

// --- prep: W fp32 -> bf16, bias sum ---------------------------------------
__global__ void prep_kernel(const float* __restrict__ Wn, const float* __restrict__ bn,
                            const float* __restrict__ Ws, const float* __restrict__ bs,
                            unsigned short* __restrict__ wnb, unsigned short* __restrict__ wsb,
                            float* __restrict__ bsum) {
  int tid = blockIdx.x * blockDim.x + threadIdx.x;
  int stride = gridDim.x * blockDim.x;
  for (int i = tid; i < DIM * DIM; i += stride) {
    wnb[i] = f2bf(Wn[i]);
    wsb[i] = f2bf(Ws[i]);
  }
  if (tid < DIM) bsum[tid] = bn[tid] + bs[tid];
}

// --- CSR build: histogram of dst ------------------------------------------
__global__ __launch_bounds__(256) void hist_kernel(const int* __restrict__ ei,
                                                   int* __restrict__ cnt) {
  int tid = blockIdx.x * blockDim.x + threadIdx.x;
  int stride = gridDim.x * blockDim.x;
  for (int e = tid; e < NE; e += stride) {
    int dst = ei[NE + e];
    if ((unsigned)dst < NN) atomicAdd(&cnt[dst], 1);
  }
}

// --- scan step 1: per-block exclusive scan + block totals ------------------
__global__ __launch_bounds__(256) void scan1_kernel(const int* __restrict__ cnt,
                                                    int* __restrict__ offs,
                                                    int* __restrict__ bsums) {
  __shared__ int s[256];
  int tid = threadIdx.x;
  int i = blockIdx.x * 256 + tid;
  int c = (i < NN) ? cnt[i] : 0;
  s[tid] = c;
  __syncthreads();
  #pragma unroll
  for (int d = 1; d < 256; d <<= 1) {
    int v = (tid >= d) ? s[tid - d] : 0;
    __syncthreads();
    if (tid >= d) s[tid] += v;
    __syncthreads();
  }
  if (i < NN) offs[i] = s[tid] - c;   // exclusive within block
  if (tid == 255) bsums[blockIdx.x] = s[255];
}

// --- scan step 2: exclusive scan of block totals (single block) -----------
__global__ __launch_bounds__(512) void scan2_kernel(int* __restrict__ bsums) {
  __shared__ int s[512];
  int tid = threadIdx.x;
  int v = (tid < NB) ? bsums[tid] : 0;
  s[tid] = v;
  __syncthreads();
  #pragma unroll
  for (int d = 1; d < 512; d <<= 1) {
    int w = (tid >= d) ? s[tid - d] : 0;
    __syncthreads();
    if (tid >= d) s[tid] += w;
    __syncthreads();
  }
  if (tid < NB) bsums[tid] = s[tid] - v;  // exclusive
}

// --- scan step 3: add block base; init cursor; offs[NN]=NE ----------------
__global__ __launch_bounds__(256) void scan3_kernel(int* __restrict__ offs,
                                                    const int* __restrict__ bsums,
                                                    int* __restrict__ cursor) {
  int tid = threadIdx.x;
  int i = blockIdx.x * 256 + tid;
  if (i < NN) {
    int o = offs[i] + bsums[blockIdx.x];
    offs[i] = o;
    cursor[i] = o;
  }
  if (blockIdx.x == 0 && tid == 0) offs[NN] = NE;
}

// --- fill: claim slot per edge, store src ---------------------------------
__global__ __launch_bounds__(256) void fill_kernel(const int* __restrict__ ei,
                                                   int* __restrict__ cursor,
                                                   int* __restrict__ csr) {
  int tid = blockIdx.x * blockDim.x + threadIdx.x;
  int stride = gridDim.x * blockDim.x;
  for (int e = tid; e < NE; e += stride) {
    int src = ei[e];
    int dst = ei[NE + e];
    if ((unsigned)src >= NN || (unsigned)dst >= NN) continue;
    int slot = atomicAdd(&cursor[dst], 1);
    csr[slot] = src;
  }
}

// --- aggregate: neigh[n] = sum over in-edges of x[src], no atomics --------
// 32 lanes per node, f32x4 per lane (512B row), 2-way unrolled edge loop.
__global__ __launch_bounds__(256) void aggregate_kernel(const float* __restrict__ x,
                                                        const int* __restrict__ offs,
                                                        const int* __restrict__ csr,
                                                        float* __restrict__ out) {
  int g = blockIdx.x * 8 + (threadIdx.x >> 5);
  if (g >= NN) return;
  int lane = threadIdx.x & 31;
  int beg = offs[g], end = offs[g + 1];
  f32x4 a0 = (f32x4){0.f, 0.f, 0.f, 0.f};
  f32x4 a1 = (f32x4){0.f, 0.f, 0.f, 0.f};
  int e = beg;
  for (; e + 1 < end; e += 2) {
    int s0 = csr[e], s1 = csr[e + 1];
    a0 += *reinterpret_cast<const f32x4*>(x + (size_t)s0 * DIM + lane * 4);
    a1 += *reinterpret_cast<const f32x4*>(x + (size_t)s1 * DIM + lane * 4);
  }
  if (e < end) {
    int s0 = csr[e];
    a0 += *reinterpret_cast<const f32x4*>(x + (size_t)s0 * DIM + lane * 4);
  }
  a0 += a1;
  *reinterpret_cast<f32x4*>(out + (size_t)g * DIM + lane * 4) = a0;
}

// --- fused GEMM: out = neigh@Wn^T + x@Ws^T + (bn+bs), in-place on out -----
__global__ __launch_bounds__(256) void gemm_kernel(const float* __restrict__ x,
    float* __restrict__ out,
    const unsigned short* __restrict__ wnb, const unsigned short* __restrict__ wsb,
    const float* __restrict__ bsum) {
  __shared__ unsigned short sW[DIM * DIM];  // 32KB
  __shared__ unsigned short sA[BM * DIM];   // 16KB neigh tile (bf16)
  __shared__ unsigned short sX[BM * DIM];   // 16KB x tile (bf16)
  const int tid = threadIdx.x;
  const int row0 = blockIdx.x * BM;

  #pragma unroll
  for (int it = 0; it < 4; ++it) {
    int id = it * 256 + tid;
    int r = id >> 4;
    int k0 = (id & 15) << 3;
    int gr = row0 + r;
    short8 an = (short8)0, ax = (short8)0;
    if (gr < NN) {
      const f32x4* pn = reinterpret_cast<const f32x4*>(out + (size_t)gr * DIM + k0);
      f32x4 n0 = pn[0], n1 = pn[1];
      const f32x4* px = reinterpret_cast<const f32x4*>(x + (size_t)gr * DIM + k0);
      f32x4 x0 = px[0], x1 = px[1];
      #pragma unroll
      for (int j = 0; j < 4; ++j) {
        an[j]     = (short)f2bf(n0[j]);
        an[4 + j] = (short)f2bf(n1[j]);
        ax[j]     = (short)f2bf(x0[j]);
        ax[4 + j] = (short)f2bf(x1[j]);
      }
    }
    int off = (r * 256 + k0 * 2) ^ ((r & 7) << 4);
    *reinterpret_cast<short8*>(reinterpret_cast<char*>(sA) + off) = an;
    *reinterpret_cast<short8*>(reinterpret_cast<char*>(sX) + off) = ax;
  }
  #pragma unroll
  for (int it = 0; it < 8; ++it) {
    int id = it * 256 + tid;
    int r = id >> 4;
    int k0 = (id & 15) << 3;
    short8 w = *reinterpret_cast<const short8*>(wnb + r * DIM + k0);
    int off = (r * 256 + k0 * 2) ^ ((r & 7) << 4);
    *reinterpret_cast<short8*>(reinterpret_cast<char*>(sW) + off) = w;
  }
  __syncthreads();

  const int wave = tid >> 6;
  const int lane = tid & 63;
  const int arow = wave * 16 + (lane & 15);
  const int kl = (lane >> 4) * 8;
  f32x4 acc[8];
  #pragma unroll
  for (int nt = 0; nt < 8; ++nt) acc[nt] = (f32x4){0.f, 0.f, 0.f, 0.f};

  // phase 1: neigh x Wn
  #pragma unroll
  for (int ks = 0; ks < 4; ++ks) {
    int k = ks * 32 + kl;
    short8 a = *reinterpret_cast<const short8*>(
        reinterpret_cast<const char*>(sA) + ((arow * 256 + k * 2) ^ ((arow & 7) << 4)));
    #pragma unroll
    for (int nt = 0; nt < 8; ++nt) {
      int o = nt * 16 + (lane & 15);
      short8 b = *reinterpret_cast<const short8*>(
          reinterpret_cast<const char*>(sW) + ((o * 256 + k * 2) ^ ((o & 7) << 4)));
      acc[nt] = __builtin_amdgcn_mfma_f32_16x16x32_bf16(a, b, acc[nt], 0, 0, 0);
    }
  }
  __syncthreads();
  #pragma unroll
  for (int it = 0; it < 8; ++it) {
    int id = it * 256 + tid;
    int r = id >> 4;
    int k0 = (id & 15) << 3;
    short8 w = *reinterpret_cast<const short8*>(wsb + r * DIM + k0);
    int off = (r * 256 + k0 * 2) ^ ((r & 7) << 4);
    *reinterpret_cast<short8*>(reinterpret_cast<char*>(sW) + off) = w;
  }
  __syncthreads();
  // phase 2: x x Ws
  #pragma unroll
  for (int ks = 0; ks < 4; ++ks) {
    int k = ks * 32 + kl;
    short8 a = *reinterpret_cast<const short8*>(
        reinterpret_cast<const char*>(sX) + ((arow * 256 + k * 2) ^ ((arow & 7) << 4)));
    #pragma unroll
    for (int nt = 0; nt < 8; ++nt) {
      int o = nt * 16 + (lane & 15);
      short8 b = *reinterpret_cast<const short8*>(
          reinterpret_cast<const char*>(sW) + ((o * 256 + k * 2) ^ ((o & 7) << 4)));
      acc[nt] = __builtin_amdgcn_mfma_f32_16x16x32_bf16(a, b, acc[nt], 0, 0, 0);
    }
  }

  // epilogue: C/D layout col=lane&15, row=(lane>>4)*4+reg  [guide m89]
  #pragma unroll
  for (int nt = 0; nt < 8; ++nt) {
    int col = nt * 16 + (lane & 15);
    float bv = bsum[col];
    #pragma unroll
    for (int reg = 0; reg < 4; ++reg) {
      int gr = row0 + wave * 16 + (lane >> 4) * 4 + reg;
      if (gr < NN) out[(size_t)gr * DIM + col] = acc[nt][reg] + bv;
    }
  }
}

extern "C" void kernel_launch(void* const* d_in, const int* in_sizes, int n_in,
                              void* d_out, int out_size, void* d_ws, size_t ws_size,
                              hipStream_t stream) {
  const float* x  = (const float*)d_in[0];
  const int*   ei = (const int*)d_in[1];
  const float* Wn = (const float*)d_in[2];
  const float* bn = (const float*)d_in[3];
  const float* Ws = (const float*)d_in[4];
  const float* bs = (const float*)d_in[5];
  float* out = (float*)d_out;

  char* ws = (char*)d_ws;
  unsigned short* wnb = (unsigned short*)(ws + 0);        // 32KB
  unsigned short* wsb = (unsigned short*)(ws + 32768);    // 32KB
  float* bsum        = (float*)(ws + 65536);              // 512B
  int* cnt           = (int*)(ws + 66560);                // 400KB
  int* offs          = (int*)(ws + 466944);               // 400KB + 4 (NN+1)
  int* cursor        = (int*)(ws + 867328);               // 400KB
  int* bsums         = (int*)(ws + 1267712);              // ~1.6KB
  int* csr           = (int*)(ws + 1269760);              // 6.4MB

  hipMemsetAsync(cnt, 0, NN * sizeof(int), stream);
  prep_kernel<<<64, 256, 0, stream>>>(Wn, bn, Ws, bs, wnb, wsb, bsum);
  hist_kernel<<<2048, 256, 0, stream>>>(ei, cnt);
  scan1_kernel<<<NB, 256, 0, stream>>>(cnt, offs, bsums);
  scan2_kernel<<<1, 512, 0, stream>>>(bsums);
  scan3_kernel<<<NB, 256, 0, stream>>>(offs, bsums, cursor);
  fill_kernel<<<2048, 256, 0, stream>>>(ei, cursor, csr);
  aggregate_kernel<<<(NN + 7) / 8, 256, 0, stream>>>(x, offs, csr, out);
  gemm_kernel<<<(NN + BM - 1) / BM, 256, 0, stream>>>(x, out, wnb, wsb, bsum);
}

// Round 5
// 229.017 us; speedup vs baseline: 11.9772x; 1.6116x over previous
//
#include <hip/hip_runtime.h>
#include <hip/hip_bf16.h>

#define NN 100000
#define NE 1600000
#define DIM 128
#define BM 64
#define NB 391   // ceil(NN/256)

typedef __attribute__((ext_vector_type(8))) short short8;
typedef __attribute__((ext_vector_type(4))) float f32x4;
typedef __attribute__((ext_vector_type(4))) unsigned short ushort4v;

__device__ __forceinline__ unsigned short f2bf(float f) {
  union { float f; unsigned u; } v; v.f = f;
  unsigned r = v.u + 0x7fffu + ((v.u >> 16) & 1u);
  return (unsigned short)(r >> 16);
}
__device__ __forceinline__ float bf2f(unsigned short h) {
  union { unsigned u; float f; } v; v.u = ((unsigned)h) << 16;
  return v.f;
}

// ========================= FULL path kernels ==============================

// x -> bf16 (xb), W -> bf16, bias sum. One streaming pass.
__global__ __launch_bounds__(256) void cvt_kernel(const float* __restrict__ x,
    const float* __restrict__ Wn, const float* __restrict__ bn,
    const float* __restrict__ Ws, const float* __restrict__ bs,
    unsigned short* __restrict__ xb, unsigned short* __restrict__ wnb,
    unsigned short* __restrict__ wsb, float* __restrict__ bsum) {
  int tid = blockIdx.x * blockDim.x + threadIdx.x;
  int stride = gridDim.x * blockDim.x;
  const int NC = NN * DIM / 4;
  for (int i = tid; i < NC; i += stride) {
    f32x4 v = reinterpret_cast<const f32x4*>(x)[i];
    ushort4v u;
    u[0] = f2bf(v[0]); u[1] = f2bf(v[1]); u[2] = f2bf(v[2]); u[3] = f2bf(v[3]);
    reinterpret_cast<ushort4v*>(xb)[i] = u;
  }
  if (tid < DIM * DIM) { wnb[tid] = f2bf(Wn[tid]); wsb[tid] = f2bf(Ws[tid]); }
  if (tid < DIM) bsum[tid] = bn[tid] + bs[tid];
}

// histogram of dst + per-edge rank (atomicAdd return) -> kills fill's chain
__global__ __launch_bounds__(256) void hist_rank_kernel(const int* __restrict__ ei,
    int* __restrict__ cnt, int* __restrict__ rank) {
  int tid = blockIdx.x * blockDim.x + threadIdx.x;
  int stride = gridDim.x * blockDim.x;
  for (int e = tid; e < NE; e += stride) {
    int dst = ei[NE + e];
    int r = 0;
    if ((unsigned)dst < NN) r = atomicAdd(&cnt[dst], 1);
    rank[e] = r;
  }
}

__global__ __launch_bounds__(256) void scan1_kernel(const int* __restrict__ cnt,
                                                    int* __restrict__ offs,
                                                    int* __restrict__ bsums) {
  __shared__ int s[256];
  int tid = threadIdx.x;
  int i = blockIdx.x * 256 + tid;
  int c = (i < NN) ? cnt[i] : 0;
  s[tid] = c;
  __syncthreads();
  #pragma unroll
  for (int d = 1; d < 256; d <<= 1) {
    int v = (tid >= d) ? s[tid - d] : 0;
    __syncthreads();
    if (tid >= d) s[tid] += v;
    __syncthreads();
  }
  if (i < NN) offs[i] = s[tid] - c;
  if (tid == 255) bsums[blockIdx.x] = s[255];
}

__global__ __launch_bounds__(512) void scan2_kernel(int* __restrict__ bsums) {
  __shared__ int s[512];
  int tid = threadIdx.x;
  int v = (tid < NB) ? bsums[tid] : 0;
  s[tid] = v;
  __syncthreads();
  #pragma unroll
  for (int d = 1; d < 512; d <<= 1) {
    int w = (tid >= d) ? s[tid - d] : 0;
    __syncthreads();
    if (tid >= d) s[tid] += w;
    __syncthreads();
  }
  if (tid < NB) bsums[tid] = s[tid] - v;
}

// add block base to offs; offs[NN]=NE (no cursor in FULL path)
__global__ __launch_bounds__(256) void scan3f_kernel(int* __restrict__ offs,
                                                     const int* __restrict__ bsums) {
  int tid = threadIdx.x;
  int i = blockIdx.x * 256 + tid;
  if (i < NN) offs[i] += bsums[blockIdx.x];
  if (blockIdx.x == 0 && tid == 0) offs[NN] = NE;
}

// atomic-free fill: slot fully determined by offs[dst]+rank[e]
__global__ __launch_bounds__(256) void fill_rank_kernel(const int* __restrict__ ei,
    const int* __restrict__ offs, const int* __restrict__ rank,
    int* __restrict__ csr) {
  int tid = blockIdx.x * blockDim.x + threadIdx.x;
  int stride = gridDim.x * blockDim.x;
  for (int e = tid; e < NE; e += stride) {
    int src = ei[e];
    int dst = ei[NE + e];
    if ((unsigned)src >= NN || (unsigned)dst >= NN) continue;
    csr[offs[dst] + rank[e]] = src;
  }
}

// fused: per-block aggregate 64 nodes (bf16 gather, fp32 accum) into LDS
// A-tile, then dual MFMA GEMM. 512 threads = 8 waves (2 blocks/CU @64KB LDS).
__global__ __launch_bounds__(512) void fusedgemm_kernel(
    const unsigned short* __restrict__ xb,
    const int* __restrict__ offs, const int* __restrict__ csr,
    const unsigned short* __restrict__ wnb, const unsigned short* __restrict__ wsb,
    const float* __restrict__ bsum, float* __restrict__ out) {
  __shared__ unsigned short sW[DIM * DIM];  // 32KB
  __shared__ unsigned short sA[BM * DIM];   // 16KB aggregated neigh (bf16)
  __shared__ unsigned short sX[BM * DIM];   // 16KB x tile (bf16)
  const int tid = threadIdx.x;
  const int row0 = blockIdx.x * BM;

  // (a) aggregate: 16 lane-groups of 32, 4 iters -> 64 nodes. 4-way unroll.
  {
    const int lg = tid >> 5, ln = tid & 31;
    for (int it = 0; it < 4; ++it) {
      int r = it * 16 + lg;
      int g = row0 + r;
      f32x4 a0 = (f32x4){0.f,0.f,0.f,0.f}, a1 = a0, a2 = a0, a3 = a0;
      if (g < NN) {
        int beg = offs[g], end = offs[g + 1];
        int e = beg;
        for (; e + 3 < end; e += 4) {
          int s0 = csr[e], s1 = csr[e+1], s2 = csr[e+2], s3 = csr[e+3];
          ushort4v u0 = *reinterpret_cast<const ushort4v*>(xb + (size_t)s0 * DIM + ln * 4);
          ushort4v u1 = *reinterpret_cast<const ushort4v*>(xb + (size_t)s1 * DIM + ln * 4);
          ushort4v u2 = *reinterpret_cast<const ushort4v*>(xb + (size_t)s2 * DIM + ln * 4);
          ushort4v u3 = *reinterpret_cast<const ushort4v*>(xb + (size_t)s3 * DIM + ln * 4);
          #pragma unroll
          for (int j = 0; j < 4; ++j) {
            a0[j] += bf2f(u0[j]); a1[j] += bf2f(u1[j]);
            a2[j] += bf2f(u2[j]); a3[j] += bf2f(u3[j]);
          }
        }
        for (; e < end; ++e) {
          int s0 = csr[e];
          ushort4v u0 = *reinterpret_cast<const ushort4v*>(xb + (size_t)s0 * DIM + ln * 4);
          #pragma unroll
          for (int j = 0; j < 4; ++j) a0[j] += bf2f(u0[j]);
        }
        a0 += a1; a2 += a3; a0 += a2;
      }
      ushort4v o;
      o[0] = f2bf(a0[0]); o[1] = f2bf(a0[1]); o[2] = f2bf(a0[2]); o[3] = f2bf(a0[3]);
      int off = (r * 256 + ln * 8) ^ ((r & 7) << 4);
      *reinterpret_cast<ushort4v*>(reinterpret_cast<char*>(sA) + off) = o;
    }
  }
  // (b) stage sX from xb (direct bf16 copy, 1024 16B-chunks, 2 iters)
  #pragma unroll
  for (int it = 0; it < 2; ++it) {
    int id = it * 512 + tid;
    int r = id >> 4, c = id & 15;
    int gr = row0 + r;
    short8 v = (short8)0;
    if (gr < NN) v = *reinterpret_cast<const short8*>(xb + (size_t)gr * DIM + c * 8);
    int off = (r * 256 + c * 16) ^ ((r & 7) << 4);
    *reinterpret_cast<short8*>(reinterpret_cast<char*>(sX) + off) = v;
  }
  // (c) stage Wn (2048 chunks, 4 iters)
  #pragma unroll
  for (int it = 0; it < 4; ++it) {
    int id = it * 512 + tid;
    int r = id >> 4, c = id & 15;
    short8 w = *reinterpret_cast<const short8*>(wnb + r * DIM + c * 8);
    int off = (r * 256 + c * 16) ^ ((r & 7) << 4);
    *reinterpret_cast<short8*>(reinterpret_cast<char*>(sW) + off) = w;
  }
  __syncthreads();

  // 8 waves: wm = M-quadrant (16 rows), wn = N-half (4 of 8 col-tiles)
  const int wave = tid >> 6;
  const int lane = tid & 63;
  const int wm = wave & 3, wn = wave >> 2;
  const int arow = wm * 16 + (lane & 15);
  const int kl = (lane >> 4) * 8;
  f32x4 acc[4];
  #pragma unroll
  for (int t = 0; t < 4; ++t) acc[t] = (f32x4){0.f, 0.f, 0.f, 0.f};

  // phase 1: neigh x Wn
  #pragma unroll
  for (int ks = 0; ks < 4; ++ks) {
    int k = ks * 32 + kl;
    short8 a = *reinterpret_cast<const short8*>(
        reinterpret_cast<const char*>(sA) + ((arow * 256 + k * 2) ^ ((arow & 7) << 4)));
    #pragma unroll
    for (int t = 0; t < 4; ++t) {
      int o = (wn * 4 + t) * 16 + (lane & 15);
      short8 b = *reinterpret_cast<const short8*>(
          reinterpret_cast<const char*>(sW) + ((o * 256 + k * 2) ^ ((o & 7) << 4)));
      acc[t] = __builtin_amdgcn_mfma_f32_16x16x32_bf16(a, b, acc[t], 0, 0, 0);
    }
  }
  __syncthreads();
  // restage Ws
  #pragma unroll
  for (int it = 0; it < 4; ++it) {
    int id = it * 512 + tid;
    int r = id >> 4, c = id & 15;
    short8 w = *reinterpret_cast<const short8*>(wsb + r * DIM + c * 8);
    int off = (r * 256 + c * 16) ^ ((r & 7) << 4);
    *reinterpret_cast<short8*>(reinterpret_cast<char*>(sW) + off) = w;
  }
  __syncthreads();
  // phase 2: x x Ws
  #pragma unroll
  for (int ks = 0; ks < 4; ++ks) {
    int k = ks * 32 + kl;
    short8 a = *reinterpret_cast<const short8*>(
        reinterpret_cast<const char*>(sX) + ((arow * 256 + k * 2) ^ ((arow & 7) << 4)));
    #pragma unroll
    for (int t = 0; t < 4; ++t) {
      int o = (wn * 4 + t) * 16 + (lane & 15);
      short8 b = *reinterpret_cast<const short8*>(
          reinterpret_cast<const char*>(sW) + ((o * 256 + k * 2) ^ ((o & 7) << 4)));
      acc[t] = __builtin_amdgcn_mfma_f32_16x16x32_bf16(a, b, acc[t], 0, 0, 0);
    }
  }

  // epilogue: C/D layout col=lane&15, row=(lane>>4)*4+reg
  #pragma unroll
  for (int t = 0; t < 4; ++t) {
    int col = (wn * 4 + t) * 16 + (lane & 15);
    float bv = bsum[col];
    #pragma unroll
    for (int reg = 0; reg < 4; ++reg) {
      int gr = row0 + wm * 16 + (lane >> 4) * 4 + reg;
      if (gr < NN) out[(size_t)gr * DIM + col] = acc[t][reg] + bv;
    }
  }
}

// ========================= SAFE (round-4, proven) =========================

__global__ void prep_kernel(const float* __restrict__ Wn, const float* __restrict__ bn,
                            const float* __restrict__ Ws, const float* __restrict__ bs,
                            unsigned short* __restrict__ wnb, unsigned short* __restrict__ wsb,
                            float* __restrict__ bsum) {
  int tid = blockIdx.x * blockDim.x + threadIdx.x;
  int stride = gridDim.x * blockDim.x;
  for (int i = tid; i < DIM * DIM; i += stride) {
    wnb[i] = f2bf(Wn[i]);
    wsb[i] = f2bf(Ws[i]);
  }
  if (tid < DIM) bsum[tid] = bn[tid] + bs[tid];
}

__global__ __launch_bounds__(256) void hist_kernel(const int* __restrict__ ei,
                                                   int* __restrict__ cnt) {
  int tid = blockIdx.x * blockDim.x + threadIdx.x;
  int stride = gridDim.x * blockDim.x;
  for (int e = tid; e < NE; e += stride) {
    int dst = ei[NE + e];
    if ((unsigned)dst < NN) atomicAdd(&cnt[dst], 1);
  }
}

__global__ __launch_bounds__(256) void scan3_kernel(int* __restrict__ offs,
                                                    const int* __restrict__ bsums,
                                                    int* __restrict__ cursor) {
  int tid = threadIdx.x;
  int i = blockIdx.x * 256 + tid;
  if (i < NN) {
    int o = offs[i] + bsums[blockIdx.x];
    offs[i] = o;
    cursor[i] = o;
  }
  if (blockIdx.x == 0 && tid == 0) offs[NN] = NE;
}

__global__ __launch_bounds__(256) void fill_kernel(const int* __restrict__ ei,
                                                   int* __restrict__ cursor,
                                                   int* __restrict__ csr) {
  int tid = blockIdx.x * blockDim.x + threadIdx.x;
  int stride = gridDim.x * blockDim.x;
  for (int e = tid; e < NE; e += stride) {
    int src = ei[e];
    int dst = ei[NE + e];
    if ((unsigned)src >= NN || (unsigned)dst >= NN) continue;
    int slot = atomicAdd(&cursor[dst], 1);
    csr[slot] = src;
  }
}

__global__ __launch_bounds__(256) void aggregate_kernel(const float* __restrict__ x,
                                                        const int* __restrict__ offs,
                                                        const int* __restrict__ csr,
                                                        float* __restrict__ out) {
  int g = blockIdx.x * 8 + (threadIdx.x >> 5);
  if (g >= NN) return;
  int lane = threadIdx.x & 31;
  int beg = offs[g], end = offs[g + 1];
  f32x4 a0 = (f32x4){0.f, 0.f, 0.f, 0.f};
  f32x4 a1 = (f32x4){0.f, 0.f, 0.f, 0.f};
  int e = beg;
  for (; e + 1 < end; e += 2) {
    int s0 = csr[e], s1 = csr[e + 1];
    a0 += *reinterpret_cast<const f32x4*>(x + (size_t)s0 * DIM + lane * 4);
    a1 += *reinterpret_cast<const f32x4*>(x + (size_t)s1 * DIM + lane * 4);
  }
  if (e < end) {
    int s0 = csr[e];
    a0 += *reinterpret_cast<const f32x4*>(x + (size_t)s0 * DIM + lane * 4);
  }
  a0 += a1;
  *reinterpret_cast<f32x4*>(out + (size_t)g * DIM + lane * 4) = a0;
}

__global__ __launch_bounds__(256) void gemm_kernel(const float* __restrict__ x,
    float* __restrict__ out,
    const unsigned short* __restrict__ wnb, const unsigned short* __restrict__ wsb,
    const float* __restrict__ bsum) {
  __shared__ unsigned short sW[DIM * DIM];
  __shared__ unsigned short sA[BM * DIM];
  __shared__ unsigned short sX[BM * DIM];
  const int tid = threadIdx.x;
  const int row0 = blockIdx.x * BM;

  #pragma unroll
  for (int it = 0; it < 4; ++it) {
    int id = it * 256 + tid;
    int r = id >> 4;
    int k0 = (id & 15) << 3;
    int gr = row0 + r;
    short8 an = (short8)0, ax = (short8)0;
    if (gr < NN) {
      const f32x4* pn = reinterpret_cast<const f32x4*>(out + (size_t)gr * DIM + k0);
      f32x4 n0 = pn[0], n1 = pn[1];
      const f32x4* px = reinterpret_cast<const f32x4*>(x + (size_t)gr * DIM + k0);
      f32x4 x0 = px[0], x1 = px[1];
      #pragma unroll
      for (int j = 0; j < 4; ++j) {
        an[j]     = (short)f2bf(n0[j]);
        an[4 + j] = (short)f2bf(n1[j]);
        ax[j]     = (short)f2bf(x0[j]);
        ax[4 + j] = (short)f2bf(x1[j]);
      }
    }
    int off = (r * 256 + k0 * 2) ^ ((r & 7) << 4);
    *reinterpret_cast<short8*>(reinterpret_cast<char*>(sA) + off) = an;
    *reinterpret_cast<short8*>(reinterpret_cast<char*>(sX) + off) = ax;
  }
  #pragma unroll
  for (int it = 0; it < 8; ++it) {
    int id = it * 256 + tid;
    int r = id >> 4;
    int k0 = (id & 15) << 3;
    short8 w = *reinterpret_cast<const short8*>(wnb + r * DIM + k0);
    int off = (r * 256 + k0 * 2) ^ ((r & 7) << 4);
    *reinterpret_cast<short8*>(reinterpret_cast<char*>(sW) + off) = w;
  }
  __syncthreads();

  const int wave = tid >> 6;
  const int lane = tid & 63;
  const int arow = wave * 16 + (lane & 15);
  const int kl = (lane >> 4) * 8;
  f32x4 acc[8];
  #pragma unroll
  for (int nt = 0; nt < 8; ++nt) acc[nt] = (f32x4){0.f, 0.f, 0.f, 0.f};

  #pragma unroll
  for (int ks = 0; ks < 4; ++ks) {
    int k = ks * 32 + kl;
    short8 a = *reinterpret_cast<const short8*>(
        reinterpret_cast<const char*>(sA) + ((arow * 256 + k * 2) ^ ((arow & 7) << 4)));
    #pragma unroll
    for (int nt = 0; nt < 8; ++nt) {
      int o = nt * 16 + (lane & 15);
      short8 b = *reinterpret_cast<const short8*>(
          reinterpret_cast<const char*>(sW) + ((o * 256 + k * 2) ^ ((o & 7) << 4)));
      acc[nt] = __builtin_amdgcn_mfma_f32_16x16x32_bf16(a, b, acc[nt], 0, 0, 0);
    }
  }
  __syncthreads();
  #pragma unroll
  for (int it = 0; it < 8; ++it) {
    int id = it * 256 + tid;
    int r = id >> 4;
    int k0 = (id & 15) << 3;
    short8 w = *reinterpret_cast<const short8*>(wsb + r * DIM + k0);
    int off = (r * 256 + k0 * 2) ^ ((r & 7) << 4);
    *reinterpret_cast<short8*>(reinterpret_cast<char*>(sW) + off) = w;
  }
  __syncthreads();
  #pragma unroll
  for (int ks = 0; ks < 4; ++ks) {
    int k = ks * 32 + kl;
    short8 a = *reinterpret_cast<const short8*>(
        reinterpret_cast<const char*>(sX) + ((arow * 256 + k * 2) ^ ((arow & 7) << 4)));
    #pragma unroll
    for (int nt = 0; nt < 8; ++nt) {
      int o = nt * 16 + (lane & 15);
      short8 b = *reinterpret_cast<const short8*>(
          reinterpret_cast<const char*>(sW) + ((o * 256 + k * 2) ^ ((o & 7) << 4)));
      acc[nt] = __builtin_amdgcn_mfma_f32_16x16x32_bf16(a, b, acc[nt], 0, 0, 0);
    }
  }

  #pragma unroll
  for (int nt = 0; nt < 8; ++nt) {
    int col = nt * 16 + (lane & 15);
    float bv = bsum[col];
    #pragma unroll
    for (int reg = 0; reg < 4; ++reg) {
      int gr = row0 + wave * 16 + (lane >> 4) * 4 + reg;
      if (gr < NN) out[(size_t)gr * DIM + col] = acc[nt][reg] + bv;
    }
  }
}

// ==========================================================================

extern "C" void kernel_launch(void* const* d_in, const int* in_sizes, int n_in,
                              void* d_out, int out_size, void* d_ws, size_t ws_size,
                              hipStream_t stream) {
  const float* x  = (const float*)d_in[0];
  const int*   ei = (const int*)d_in[1];
  const float* Wn = (const float*)d_in[2];
  const float* bn = (const float*)d_in[3];
  const float* Ws = (const float*)d_in[4];
  const float* bs = (const float*)d_in[5];
  float* out = (float*)d_out;
  char* ws = (char*)d_ws;

  const size_t NEED_FULL = 39268480;  // through xb
  if (ws_size >= NEED_FULL) {
    unsigned short* wnb = (unsigned short*)(ws + 0);
    unsigned short* wsb = (unsigned short*)(ws + 32768);
    float* bsum        = (float*)(ws + 65536);
    int* cnt           = (int*)(ws + 66560);
    int* offs          = (int*)(ws + 466560);
    int* bsums         = (int*)(ws + 866816);
    int* rank          = (int*)(ws + 868480);
    int* csr           = (int*)(ws + 7268480);
    unsigned short* xb = (unsigned short*)(ws + 13668480);

    hipMemsetAsync(cnt, 0, NN * sizeof(int), stream);
    cvt_kernel<<<2048, 256, 0, stream>>>(x, Wn, bn, Ws, bs, xb, wnb, wsb, bsum);
    hist_rank_kernel<<<2048, 256, 0, stream>>>(ei, cnt, rank);
    scan1_kernel<<<NB, 256, 0, stream>>>(cnt, offs, bsums);
    scan2_kernel<<<1, 512, 0, stream>>>(bsums);
    scan3f_kernel<<<NB, 256, 0, stream>>>(offs, bsums);
    fill_rank_kernel<<<2048, 256, 0, stream>>>(ei, offs, rank, csr);
    fusedgemm_kernel<<<(NN + BM - 1) / BM, 512, 0, stream>>>(xb, offs, csr, wnb, wsb, bsum, out);
  } else {
    unsigned short* wnb = (unsigned short*)(ws + 0);
    unsigned short* wsb = (unsigned short*)(ws + 32768);
    float* bsum        = (float*)(ws + 65536);
    int* cnt           = (int*)(ws + 66560);
    int* offs          = (int*)(ws + 466944);
    int* cursor        = (int*)(ws + 867328);
    int* bsums         = (int*)(ws + 1267712);
    int* csr           = (int*)(ws + 1269760);

    hipMemsetAsync(cnt, 0, NN * sizeof(int), stream);
    prep_kernel<<<64, 256, 0, stream>>>(Wn, bn, Ws, bs, wnb, wsb, bsum);
    hist_kernel<<<2048, 256, 0, stream>>>(ei, cnt);
    scan1_kernel<<<NB, 256, 0, stream>>>(cnt, offs, bsums);
    scan2_kernel<<<1, 512, 0, stream>>>(bsums);
    scan3_kernel<<<NB, 256, 0, stream>>>(offs, bsums, cursor);
    fill_kernel<<<2048, 256, 0, stream>>>(ei, cursor, csr);
    aggregate_kernel<<<(NN + 7) / 8, 256, 0, stream>>>(x, offs, csr, out);
    gemm_kernel<<<(NN + BM - 1) / BM, 256, 0, stream>>>(x, out, wnb, wsb, bsum);
  }
}

// Round 6
// 193.361 us; speedup vs baseline: 14.1858x; 1.1844x over previous
//
#include <hip/hip_runtime.h>
#include <hip/hip_bf16.h>

#define NN 100000
#define NE 1600000
#define DIM 128
#define BM 64
#define CAP 28
#define OVFCAP 131072
#define CVT_BLK 1024
#define SC_BLK 1024

typedef __attribute__((ext_vector_type(8))) short short8;
typedef __attribute__((ext_vector_type(4))) float f32x4;
typedef __attribute__((ext_vector_type(4))) unsigned short ushort4v;

__device__ __forceinline__ unsigned short f2bf(float f) {
  union { float f; unsigned u; } v; v.f = f;
  unsigned r = v.u + 0x7fffu + ((v.u >> 16) & 1u);
  return (unsigned short)(r >> 16);
}
__device__ __forceinline__ float bf2f(unsigned short h) {
  union { unsigned u; float f; } v; v.u = ((unsigned)h) << 16;
  return v.f;
}

// K1: blocks [0,CVT_BLK) convert x->bf16 (+W,bias); blocks [CVT_BLK,..) scatter
// edges into fixed-capacity per-node slot arrays (overflow -> small list).
__global__ __launch_bounds__(256) void prep_scatter_kernel(
    const float* __restrict__ x, const int* __restrict__ ei,
    const float* __restrict__ Wn, const float* __restrict__ bn,
    const float* __restrict__ Ws, const float* __restrict__ bs,
    unsigned short* __restrict__ xb, unsigned short* __restrict__ wnb,
    unsigned short* __restrict__ wsb, float* __restrict__ bsum,
    int* __restrict__ cnt, int* __restrict__ ovfcnt, int2* __restrict__ ovf,
    int* __restrict__ slots) {
  int b = blockIdx.x;
  if (b < CVT_BLK) {
    int tid = b * 256 + threadIdx.x;
    const int stride = CVT_BLK * 256;
    const int NC = NN * DIM / 4;
    for (int i = tid; i < NC; i += stride) {
      f32x4 v = reinterpret_cast<const f32x4*>(x)[i];
      ushort4v u;
      u[0] = f2bf(v[0]); u[1] = f2bf(v[1]); u[2] = f2bf(v[2]); u[3] = f2bf(v[3]);
      reinterpret_cast<ushort4v*>(xb)[i] = u;
    }
    if (tid < DIM * DIM) { wnb[tid] = f2bf(Wn[tid]); wsb[tid] = f2bf(Ws[tid]); }
    if (tid < DIM) bsum[tid] = bn[tid] + bs[tid];
  } else {
    int tid = (b - CVT_BLK) * 256 + threadIdx.x;
    const int stride = SC_BLK * 256;
    for (int e = tid; e < NE; e += stride) {
      int src = ei[e];
      int dst = ei[NE + e];
      if ((unsigned)src >= NN || (unsigned)dst >= NN) continue;
      int r = atomicAdd(&cnt[dst], 1);
      if (r < CAP) {
        slots[dst * CAP + r] = src;
      } else {
        int o = atomicAdd(ovfcnt, 1);
        if (o < OVFCAP) ovf[o] = make_int2(dst, src);
      }
    }
  }
}

// K2: fused aggregate (slot gather, shuffle-broadcast indices, 8-deep MLP)
// + dual bf16 MFMA GEMM. 512 thr = 8 waves; LDS ~66KB -> 2 blocks/CU.
__global__ __launch_bounds__(512) void fusedgemm_kernel(
    const unsigned short* __restrict__ xb,
    const int* __restrict__ cnt, const int* __restrict__ slots,
    const int2* __restrict__ ovf, const int* __restrict__ ovfcnt,
    const unsigned short* __restrict__ wnb, const unsigned short* __restrict__ wsb,
    const float* __restrict__ bsum, float* __restrict__ out) {
  __shared__ unsigned short sW[DIM * DIM];  // 32KB
  __shared__ unsigned short sA[BM * DIM];   // 16KB
  __shared__ unsigned short sX[BM * DIM];   // 16KB
  __shared__ int2 lovf[256];
  __shared__ int lovfn;
  const int tid = threadIdx.x;
  const int row0 = blockIdx.x * BM;

  if (tid == 0) lovfn = 0;
  // stage sX (self features, bf16 direct)
  #pragma unroll
  for (int it = 0; it < 2; ++it) {
    int id = it * 512 + tid;
    int r = id >> 4, c = id & 15;
    int gr = row0 + r;
    short8 v = (short8)0;
    if (gr < NN) v = *reinterpret_cast<const short8*>(xb + (size_t)gr * DIM + c * 8);
    int off = (r * 256 + c * 16) ^ ((r & 7) << 4);
    *reinterpret_cast<short8*>(reinterpret_cast<char*>(sX) + off) = v;
  }
  // stage sW = Wn
  #pragma unroll
  for (int it = 0; it < 4; ++it) {
    int id = it * 512 + tid;
    int r = id >> 4, c = id & 15;
    short8 w = *reinterpret_cast<const short8*>(wnb + r * DIM + c * 8);
    int off = (r * 256 + c * 16) ^ ((r & 7) << 4);
    *reinterpret_cast<short8*>(reinterpret_cast<char*>(sW) + off) = w;
  }
  __syncthreads();   // lovfn init visible

  // pick this block's overflow pairs into LDS (expected 0-2)
  {
    int ovfn = min(*ovfcnt, OVFCAP);
    for (int k = tid; k < ovfn; k += 512) {
      int2 p = ovf[k];
      if ((unsigned)(p.x - row0) < (unsigned)BM) {
        int t = atomicAdd(&lovfn, 1);
        if (t < 256) lovf[t] = p;
      }
    }
  }
  __syncthreads();   // lovf complete

  // aggregate: 16 groups x 32 lanes; 4 nodes per group; idx prefetch 1 ahead
  {
    const int lg = tid >> 5, ln = tid & 31;
    int g = row0 + lg;
    int m = 0, idx = 0;
    if (g < NN) {
      m = min(cnt[g], CAP);
      if (ln < m) idx = slots[g * CAP + ln];
    }
    const int lcnt = min(lovfn, 256);
    for (int it = 0; it < 4; ++it) {
      int r = it * 16 + lg;
      int gcur = row0 + r;
      // prefetch next node's meta/indices
      int mn = 0, idxn = 0;
      if (it < 3) {
        int gn = row0 + (it + 1) * 16 + lg;
        if (gn < NN) {
          mn = min(cnt[gn], CAP);
          if (ln < mn) idxn = slots[gn * CAP + ln];
        }
      }
      f32x4 a0 = (f32x4){0.f,0.f,0.f,0.f}, a1 = a0, a2 = a0, a3 = a0;
      f32x4 a4 = a0, a5 = a0, a6 = a0, a7 = a0;
      int e = 0;
      for (; e + 7 < m; e += 8) {
        int s0 = __shfl(idx, e, 32),     s1 = __shfl(idx, e + 1, 32);
        int s2 = __shfl(idx, e + 2, 32), s3 = __shfl(idx, e + 3, 32);
        int s4 = __shfl(idx, e + 4, 32), s5 = __shfl(idx, e + 5, 32);
        int s6 = __shfl(idx, e + 6, 32), s7 = __shfl(idx, e + 7, 32);
        ushort4v u0 = *reinterpret_cast<const ushort4v*>(xb + (size_t)s0 * DIM + ln * 4);
        ushort4v u1 = *reinterpret_cast<const ushort4v*>(xb + (size_t)s1 * DIM + ln * 4);
        ushort4v u2 = *reinterpret_cast<const ushort4v*>(xb + (size_t)s2 * DIM + ln * 4);
        ushort4v u3 = *reinterpret_cast<const ushort4v*>(xb + (size_t)s3 * DIM + ln * 4);
        ushort4v u4 = *reinterpret_cast<const ushort4v*>(xb + (size_t)s4 * DIM + ln * 4);
        ushort4v u5 = *reinterpret_cast<const ushort4v*>(xb + (size_t)s5 * DIM + ln * 4);
        ushort4v u6 = *reinterpret_cast<const ushort4v*>(xb + (size_t)s6 * DIM + ln * 4);
        ushort4v u7 = *reinterpret_cast<const ushort4v*>(xb + (size_t)s7 * DIM + ln * 4);
        #pragma unroll
        for (int j = 0; j < 4; ++j) {
          a0[j] += bf2f(u0[j]); a1[j] += bf2f(u1[j]);
          a2[j] += bf2f(u2[j]); a3[j] += bf2f(u3[j]);
          a4[j] += bf2f(u4[j]); a5[j] += bf2f(u5[j]);
          a6[j] += bf2f(u6[j]); a7[j] += bf2f(u7[j]);
        }
      }
      for (; e + 3 < m; e += 4) {
        int s0 = __shfl(idx, e, 32),     s1 = __shfl(idx, e + 1, 32);
        int s2 = __shfl(idx, e + 2, 32), s3 = __shfl(idx, e + 3, 32);
        ushort4v u0 = *reinterpret_cast<const ushort4v*>(xb + (size_t)s0 * DIM + ln * 4);
        ushort4v u1 = *reinterpret_cast<const ushort4v*>(xb + (size_t)s1 * DIM + ln * 4);
        ushort4v u2 = *reinterpret_cast<const ushort4v*>(xb + (size_t)s2 * DIM + ln * 4);
        ushort4v u3 = *reinterpret_cast<const ushort4v*>(xb + (size_t)s3 * DIM + ln * 4);
        #pragma unroll
        for (int j = 0; j < 4; ++j) {
          a0[j] += bf2f(u0[j]); a1[j] += bf2f(u1[j]);
          a2[j] += bf2f(u2[j]); a3[j] += bf2f(u3[j]);
        }
      }
      for (; e < m; ++e) {
        int s0 = __shfl(idx, e, 32);
        ushort4v u0 = *reinterpret_cast<const ushort4v*>(xb + (size_t)s0 * DIM + ln * 4);
        #pragma unroll
        for (int j = 0; j < 4; ++j) a0[j] += bf2f(u0[j]);
      }
      // overflow edges for this node
      for (int k2 = 0; k2 < lcnt; ++k2) {
        int2 p = lovf[k2];
        if (p.x == gcur) {
          ushort4v u0 = *reinterpret_cast<const ushort4v*>(xb + (size_t)p.y * DIM + ln * 4);
          #pragma unroll
          for (int j = 0; j < 4; ++j) a0[j] += bf2f(u0[j]);
        }
      }
      a0 += a1; a2 += a3; a4 += a5; a6 += a7;
      a0 += a2; a4 += a6; a0 += a4;
      ushort4v o;
      o[0] = f2bf(a0[0]); o[1] = f2bf(a0[1]); o[2] = f2bf(a0[2]); o[3] = f2bf(a0[3]);
      int off = (r * 256 + ln * 8) ^ ((r & 7) << 4);
      *reinterpret_cast<ushort4v*>(reinterpret_cast<char*>(sA) + off) = o;
      idx = idxn; m = mn;
    }
  }
  __syncthreads();

  const int wave = tid >> 6;
  const int lane = tid & 63;
  const int wm = wave & 3, wn = wave >> 2;
  const int arow = wm * 16 + (lane & 15);
  const int kl = (lane >> 4) * 8;
  f32x4 acc[4];
  #pragma unroll
  for (int t = 0; t < 4; ++t) acc[t] = (f32x4){0.f, 0.f, 0.f, 0.f};

  // phase 1: neigh x Wn
  #pragma unroll
  for (int ks = 0; ks < 4; ++ks) {
    int k = ks * 32 + kl;
    short8 a = *reinterpret_cast<const short8*>(
        reinterpret_cast<const char*>(sA) + ((arow * 256 + k * 2) ^ ((arow & 7) << 4)));
    #pragma unroll
    for (int t = 0; t < 4; ++t) {
      int o = (wn * 4 + t) * 16 + (lane & 15);
      short8 bfr = *reinterpret_cast<const short8*>(
          reinterpret_cast<const char*>(sW) + ((o * 256 + k * 2) ^ ((o & 7) << 4)));
      acc[t] = __builtin_amdgcn_mfma_f32_16x16x32_bf16(a, bfr, acc[t], 0, 0, 0);
    }
  }
  __syncthreads();
  // restage sW = Ws
  #pragma unroll
  for (int it = 0; it < 4; ++it) {
    int id = it * 512 + tid;
    int r = id >> 4, c = id & 15;
    short8 w = *reinterpret_cast<const short8*>(wsb + r * DIM + c * 8);
    int off = (r * 256 + c * 16) ^ ((r & 7) << 4);
    *reinterpret_cast<short8*>(reinterpret_cast<char*>(sW) + off) = w;
  }
  __syncthreads();
  // phase 2: x x Ws
  #pragma unroll
  for (int ks = 0; ks < 4; ++ks) {
    int k = ks * 32 + kl;
    short8 a = *reinterpret_cast<const short8*>(
        reinterpret_cast<const char*>(sX) + ((arow * 256 + k * 2) ^ ((arow & 7) << 4)));
    #pragma unroll
    for (int t = 0; t < 4; ++t) {
      int o = (wn * 4 + t) * 16 + (lane & 15);
      short8 bfr = *reinterpret_cast<const short8*>(
          reinterpret_cast<const char*>(sW) + ((o * 256 + k * 2) ^ ((o & 7) << 4)));
      acc[t] = __builtin_amdgcn_mfma_f32_16x16x32_bf16(a, bfr, acc[t], 0, 0, 0);
    }
  }

  // epilogue: C/D layout col=lane&15, row=(lane>>4)*4+reg
  #pragma unroll
  for (int t = 0; t < 4; ++t) {
    int col = (wn * 4 + t) * 16 + (lane & 15);
    float bv = bsum[col];
    #pragma unroll
    for (int reg = 0; reg < 4; ++reg) {
      int gr = row0 + wm * 16 + (lane >> 4) * 4 + reg;
      if (gr < NN) out[(size_t)gr * DIM + col] = acc[t][reg] + bv;
    }
  }
}

extern "C" void kernel_launch(void* const* d_in, const int* in_sizes, int n_in,
                              void* d_out, int out_size, void* d_ws, size_t ws_size,
                              hipStream_t stream) {
  const float* x  = (const float*)d_in[0];
  const int*   ei = (const int*)d_in[1];
  const float* Wn = (const float*)d_in[2];
  const float* bn = (const float*)d_in[3];
  const float* Ws = (const float*)d_in[4];
  const float* bs = (const float*)d_in[5];
  float* out = (float*)d_out;
  char* ws = (char*)d_ws;

  // layout (total ~38.3MB; proven ws >= 39.27MB)
  unsigned short* wnb = (unsigned short*)(ws + 0);         // 32KB
  unsigned short* wsb = (unsigned short*)(ws + 32768);     // 32KB
  float* bsum        = (float*)(ws + 65536);               // 512B
  int* cnt           = (int*)(ws + 66560);                 // 400000B
  int* ovfcnt        = (int*)(ws + 466560);                // 4B (+pad)
  int2* ovf          = (int2*)(ws + 466688);               // 1MB
  int* slots         = (int*)(ws + 1515264);               // 11.2MB
  unsigned short* xb = (unsigned short*)(ws + 12715264);   // 25.6MB

  hipMemsetAsync(cnt, 0, 400064, stream);  // cnt + ovfcnt
  prep_scatter_kernel<<<CVT_BLK + SC_BLK, 256, 0, stream>>>(
      x, ei, Wn, bn, Ws, bs, xb, wnb, wsb, bsum, cnt, ovfcnt, ovf, slots);
  fusedgemm_kernel<<<(NN + BM - 1) / BM, 512, 0, stream>>>(
      xb, cnt, slots, ovf, ovfcnt, wnb, wsb, bsum, out);
}